// Round 9
// baseline (374.482 us; speedup 1.0000x reference)
//
#include <hip/hip_runtime.h>
#include <math.h>

// Problem constants (match reference)
#define HID 256
#define DXIN 128
#define EMBD 32
#define OUTD 128
#define NLAYER 3
#define NGRAPH 8
#define LN_EPS 1e-5f
#define BKP 264   // LDS row stride (bf16 elems): 33 quads, 33%8==1 -> uniform banks
#define NBLK 256  // blocks for edge-binning passes

typedef short s8v __attribute__((ext_vector_type(8)));
typedef float f4v __attribute__((ext_vector_type(4)));
typedef float f2v __attribute__((ext_vector_type(2)));

__device__ __forceinline__ float b2f_lo(unsigned int u) {
  return __builtin_bit_cast(float, u << 16);
}
__device__ __forceinline__ float b2f_hi(unsigned int u) {
  return __builtin_bit_cast(float, u & 0xffff0000u);
}
__device__ __forceinline__ unsigned short f2b(float f) {
  unsigned int x = __builtin_bit_cast(unsigned int, f);
  unsigned int lsb = (x >> 16) & 1u;
  x += 0x7fffu + lsb;
  return (unsigned short)(x >> 16);
}

// ---------------------------------------------------------------------------
// CSR build via two-level counting sort (no global data atomics).
// bucket = dst >> 8 (<=256 buckets), dloc = dst & 255.
// ---------------------------------------------------------------------------
__global__ __launch_bounds__(256) void k_b1(const int* __restrict__ dst,
                                            int* __restrict__ blk_cnt, int E, int epb) {
  __shared__ int hist[256];
  int blk = blockIdx.x, tid = threadIdx.x;
  hist[tid] = 0;
  __syncthreads();
  int beg = blk * epb, end = min(E, beg + epb);
  for (int i = beg + tid; i < end; i += 256)
    atomicAdd(&hist[dst[i] >> 8], 1);
  __syncthreads();
  blk_cnt[blk * 256 + tid] = hist[tid];
}

__global__ __launch_bounds__(256) void k_bsum(const int* __restrict__ blk_cnt,
                                              int* __restrict__ bucket_cnt) {
  __shared__ int red[4];
  int b = blockIdx.x, tid = threadIdx.x;
  int v = blk_cnt[tid * 256 + b];
#pragma unroll
  for (int o = 32; o > 0; o >>= 1) v += __shfl_xor(v, o, 64);
  if ((tid & 63) == 0) red[tid >> 6] = v;
  __syncthreads();
  if (tid == 0) bucket_cnt[b] = red[0] + red[1] + red[2] + red[3];
}

__global__ __launch_bounds__(256) void k_bscan(const int* __restrict__ bucket_cnt,
                                               int* __restrict__ bucket_base,
                                               int* __restrict__ row_ptr,
                                               int N, int nbuck, int E) {
  __shared__ int s[256];
  int tid = threadIdx.x;
  int v = (tid < nbuck) ? bucket_cnt[tid] : 0;
  s[tid] = v;
  __syncthreads();
  for (int off = 1; off < 256; off <<= 1) {
    int t = (tid >= off) ? s[tid - off] : 0;
    __syncthreads();
    s[tid] += t;
    __syncthreads();
  }
  if (tid < nbuck) bucket_base[tid] = s[tid] - v;
  if (tid == 0) { bucket_base[nbuck] = E; row_ptr[N] = E; }
}

__global__ __launch_bounds__(256) void k_boff(const int* __restrict__ blk_cnt,
                                              const int* __restrict__ bucket_base,
                                              int* __restrict__ blk_off) {
  __shared__ int s[256];
  int b = blockIdx.x, tid = threadIdx.x;
  int v = blk_cnt[tid * 256 + b];
  s[tid] = v;
  __syncthreads();
  for (int off = 1; off < 256; off <<= 1) {
    int t = (tid >= off) ? s[tid - off] : 0;
    __syncthreads();
    s[tid] += t;
    __syncthreads();
  }
  blk_off[tid * 256 + b] = bucket_base[b] + s[tid] - v;
}

__global__ __launch_bounds__(256) void k_b3(const int* __restrict__ ei,
                                            const int* __restrict__ blk_off,
                                            unsigned int* __restrict__ pairs,
                                            int E, int epb) {
  __shared__ int cur[256];
  int blk = blockIdx.x, tid = threadIdx.x;
  cur[tid] = blk_off[blk * 256 + tid];
  __syncthreads();
  int beg = blk * epb, end = min(E, beg + epb);
  for (int i = beg + tid; i < end; i += 256) {
    int s = ei[i];
    int d = ei[E + i];
    int pos = atomicAdd(&cur[d >> 8], 1);
    pairs[pos] = (unsigned int)s | ((unsigned int)(d & 255) << 16);
  }
}

__global__ __launch_bounds__(256) void k_b4(const unsigned int* __restrict__ pairs,
                                            const int* __restrict__ bucket_base,
                                            int* __restrict__ row_ptr,
                                            float* __restrict__ dinv,
                                            int* __restrict__ col_idx, int N) {
  __shared__ int cnt[256];
  __shared__ int s[256];
  int b = blockIdx.x, tid = threadIdx.x;
  int base = bucket_base[b], end = bucket_base[b + 1];
  cnt[tid] = 0;
  __syncthreads();
  for (int i = base + tid; i < end; i += 256)
    atomicAdd(&cnt[pairs[i] >> 16], 1);
  __syncthreads();
  int c = cnt[tid];
  s[tid] = c;
  __syncthreads();
  for (int off = 1; off < 256; off <<= 1) {
    int t = (tid >= off) ? s[tid - off] : 0;
    __syncthreads();
    s[tid] += t;
    __syncthreads();
  }
  int excl = s[tid] - c;
  int d = (b << 8) + tid;
  if (d < N) {
    row_ptr[d] = base + excl;
    dinv[d] = rsqrtf((float)(c + 1));
  }
  __syncthreads();
  cnt[tid] = base + excl;  // reuse as cursor
  __syncthreads();
  for (int i = base + tid; i < end; i += 256) {
    unsigned int w = pairs[i];
    int pos = atomicAdd(&cnt[w >> 16], 1);
    col_idx[pos] = (int)(w & 0xFFFFu);
  }
}

// ---------------------------------------------------------------------------
// Weight pack (ALL weights in one launch): W [K][C] fp32 -> bf16 B-fragments.
// ---------------------------------------------------------------------------
#define T_IN  (16 * 5 * 512)
#define T_SQ  (16 * 8 * 512)
#define T_OUT (8 * 8 * 512)
__global__ void k_pack_all(const float* __restrict__ W_in, const float* __restrict__ Ws,
                           const float* __restrict__ W_out,
                           unsigned short* __restrict__ pk_in,
                           unsigned short* __restrict__ pk_sq,
                           unsigned short* __restrict__ pk_out) {
  int t = blockIdx.x * 256 + threadIdx.x;
  const float* W;
  unsigned short* dst;
  int C, NKS;
  if (t < T_IN) {
    W = W_in; dst = pk_in; C = HID; NKS = 5;
  } else if (t < T_IN + 3 * T_SQ) {
    int tt = t - T_IN;
    int lyr = tt / T_SQ;
    t = tt - lyr * T_SQ;
    W = Ws + (size_t)lyr * HID * HID; dst = pk_sq + (size_t)lyr * T_SQ; C = HID; NKS = 8;
  } else if (t < T_IN + 3 * T_SQ + T_OUT) {
    t = t - T_IN - 3 * T_SQ;
    W = W_out; dst = pk_out; C = OUTD; NKS = 8;
  } else {
    return;
  }
  int j = t & 7;
  int l = (t >> 3) & 63;
  int rest = t >> 9;
  int ks = rest % NKS;
  int ct = rest / NKS;
  int k = ks * 32 + ((l >> 4) << 3) + j;
  int c = ct * 16 + (l & 15);
  dst[t] = f2b(W[(size_t)k * C + c]);
}

// ---------------------------------------------------------------------------
// MFMA GEMM: input projection  h = relu(concat(x, emb[nt]) @ W_in + b_in)
// ---------------------------------------------------------------------------
__global__ __launch_bounds__(256) void k_mfma_in(
    const float* __restrict__ x, const int* __restrict__ nt, const float* __restrict__ emb,
    const unsigned short* __restrict__ Wpk, const float* __restrict__ bias,
    unsigned short* __restrict__ h, int N) {
  __shared__ unsigned short a_lds[64 * BKP];
  int tid = threadIdx.x;
  int w = tid >> 6, l = tid & 63;
  int row0 = blockIdx.x * 64;

  for (int i = 0; i < 4; ++i) {
    int cc = i * 256 + tid;
    int r = cc >> 4, ch = cc & 15;
    int row = row0 + r;
    unsigned short tmp[8];
    if (row < N) {
      const float* xr = &x[(size_t)row * DXIN + ch * 8];
      float4 v0 = *(const float4*)xr;
      float4 v1 = *(const float4*)(xr + 4);
      tmp[0] = f2b(v0.x); tmp[1] = f2b(v0.y); tmp[2] = f2b(v0.z); tmp[3] = f2b(v0.w);
      tmp[4] = f2b(v1.x); tmp[5] = f2b(v1.y); tmp[6] = f2b(v1.z); tmp[7] = f2b(v1.w);
    } else {
      for (int q = 0; q < 8; ++q) tmp[q] = 0;
    }
    *(uint4*)&a_lds[r * BKP + ch * 8] = *(const uint4*)tmp;
  }
  {
    int r = tid >> 2, ch = tid & 3;
    int row = row0 + r;
    unsigned short tmp[8];
    if (row < N) {
      int typ = nt[row];
      const float* er = &emb[typ * EMBD + ch * 8];
      float4 v0 = *(const float4*)er;
      float4 v1 = *(const float4*)(er + 4);
      tmp[0] = f2b(v0.x); tmp[1] = f2b(v0.y); tmp[2] = f2b(v0.z); tmp[3] = f2b(v0.w);
      tmp[4] = f2b(v1.x); tmp[5] = f2b(v1.y); tmp[6] = f2b(v1.z); tmp[7] = f2b(v1.w);
    } else {
      for (int q = 0; q < 8; ++q) tmp[q] = 0;
    }
    *(uint4*)&a_lds[r * BKP + DXIN + ch * 8] = *(const uint4*)tmp;
  }
  __syncthreads();

  f4v acc[4][4];
#pragma unroll
  for (int rt = 0; rt < 4; ++rt)
#pragma unroll
    for (int ct = 0; ct < 4; ++ct) acc[rt][ct] = (f4v)0.f;

  for (int ks = 0; ks < 5; ++ks) {
    s8v af[4];
#pragma unroll
    for (int rt = 0; rt < 4; ++rt)
      af[rt] = *(const s8v*)&a_lds[(rt * 16 + (l & 15)) * BKP + ks * 32 + (l >> 4) * 8];
#pragma unroll
    for (int ct = 0; ct < 4; ++ct) {
      s8v bf = *(const s8v*)&Wpk[(size_t)(((w * 4 + ct) * 5 + ks) * 64 + l) * 8];
#pragma unroll
      for (int rt = 0; rt < 4; ++rt)
        acc[rt][ct] = __builtin_amdgcn_mfma_f32_16x16x32_bf16(af[rt], bf, acc[rt][ct], 0, 0, 0);
    }
  }
  __syncthreads();

#pragma unroll
  for (int rt = 0; rt < 4; ++rt)
#pragma unroll
    for (int ct = 0; ct < 4; ++ct) {
      int col = w * 64 + ct * 16 + (l & 15);
      float bv = bias[col];
#pragma unroll
      for (int reg = 0; reg < 4; ++reg) {
        int r = rt * 16 + (l >> 4) * 4 + reg;
        a_lds[r * BKP + col] = f2b(fmaxf(acc[rt][ct][reg] + bv, 0.f));
      }
    }
  __syncthreads();
  for (int i = 0; i < 8; ++i) {
    int cc = i * 256 + tid;
    int r = cc >> 5, ch = cc & 31;
    int row = row0 + r;
    if (row < N)
      *(uint4*)&h[(size_t)row * HID + ch * 8] = *(const uint4*)&a_lds[r * BKP + ch * 8];
  }
}

// ---------------------------------------------------------------------------
// MFMA GEMM: square layer  m8 = fp8((h @ W) * dinv[row])  (pre-scaled by src norm)
// ---------------------------------------------------------------------------
__global__ __launch_bounds__(256) void k_mfma_sq(
    const unsigned short* __restrict__ A, const unsigned short* __restrict__ Wpk,
    const float* __restrict__ dinv, unsigned char* __restrict__ m8, int N) {
  __shared__ unsigned short a_lds[64 * BKP];
  int tid = threadIdx.x;
  int w = tid >> 6, l = tid & 63;
  int row0 = blockIdx.x * 64;

  for (int i = 0; i < 8; ++i) {
    int cc = i * 256 + tid;
    int r = cc >> 5, ch = cc & 31;
    int row = row0 + r;
    uint4 v = make_uint4(0u, 0u, 0u, 0u);
    if (row < N) v = *(const uint4*)&A[(size_t)row * HID + ch * 8];
    *(uint4*)&a_lds[r * BKP + ch * 8] = v;
  }
  __syncthreads();

  f4v acc[4][4];
#pragma unroll
  for (int rt = 0; rt < 4; ++rt)
#pragma unroll
    for (int ct = 0; ct < 4; ++ct) acc[rt][ct] = (f4v)0.f;

  for (int ks = 0; ks < 8; ++ks) {
    s8v af[4];
#pragma unroll
    for (int rt = 0; rt < 4; ++rt)
      af[rt] = *(const s8v*)&a_lds[(rt * 16 + (l & 15)) * BKP + ks * 32 + (l >> 4) * 8];
#pragma unroll
    for (int ct = 0; ct < 4; ++ct) {
      s8v bf = *(const s8v*)&Wpk[(size_t)(((w * 4 + ct) * 8 + ks) * 64 + l) * 8];
#pragma unroll
      for (int rt = 0; rt < 4; ++rt)
        acc[rt][ct] = __builtin_amdgcn_mfma_f32_16x16x32_bf16(af[rt], bf, acc[rt][ct], 0, 0, 0);
    }
  }
  __syncthreads();

  // transpose via LDS (bf16), then scale by dinv[row] + convert to fp8 on store
#pragma unroll
  for (int rt = 0; rt < 4; ++rt)
#pragma unroll
    for (int ct = 0; ct < 4; ++ct) {
      int col = w * 64 + ct * 16 + (l & 15);
#pragma unroll
      for (int reg = 0; reg < 4; ++reg) {
        int r = rt * 16 + (l >> 4) * 4 + reg;
        a_lds[r * BKP + col] = f2b(acc[rt][ct][reg]);
      }
    }
  __syncthreads();
  for (int i = 0; i < 8; ++i) {
    int cc = i * 256 + tid;
    int r = cc >> 5, ch = cc & 31;
    int row = row0 + r;
    if (row < N) {
      float dv = dinv[row];
      uint4 v = *(const uint4*)&a_lds[r * BKP + ch * 8];
      float f0 = b2f_lo(v.x) * dv, f1 = b2f_hi(v.x) * dv;
      float f2 = b2f_lo(v.y) * dv, f3 = b2f_hi(v.y) * dv;
      float f4 = b2f_lo(v.z) * dv, f5 = b2f_hi(v.z) * dv;
      float f6 = b2f_lo(v.w) * dv, f7 = b2f_hi(v.w) * dv;
      unsigned int p0 = 0, p1 = 0;
      p0 = __builtin_amdgcn_cvt_pk_fp8_f32(f0, f1, p0, 0);
      p0 = __builtin_amdgcn_cvt_pk_fp8_f32(f2, f3, p0, 1);
      p1 = __builtin_amdgcn_cvt_pk_fp8_f32(f4, f5, p1, 0);
      p1 = __builtin_amdgcn_cvt_pk_fp8_f32(f6, f7, p1, 1);
      *(uint2*)&m8[(size_t)row * HID + ch * 8] = make_uint2(p0, p1);
    }
  }
}

// ---------------------------------------------------------------------------
// MFMA GEMM: output layer (C=128) + bias + mean-pool partials via LDS bins.
// ---------------------------------------------------------------------------
__global__ __launch_bounds__(256) void k_mfma_out_pool(
    const unsigned short* __restrict__ A, const unsigned short* __restrict__ Wpk,
    const float* __restrict__ bias, const int* __restrict__ batch,
    float* __restrict__ psum, int N) {
  __shared__ unsigned short a_lds[64 * BKP];
  __shared__ float pool[NGRAPH * OUTD];
  __shared__ int b_s[64];
  int tid = threadIdx.x;
  int w = tid >> 6, l = tid & 63;
  int row0 = blockIdx.x * 64;

#pragma unroll
  for (int i = 0; i < 4; ++i) pool[tid * 4 + i] = 0.f;
  if (tid < 64) b_s[tid] = (row0 + tid < N) ? batch[row0 + tid] : -1;

  for (int i = 0; i < 8; ++i) {
    int cc = i * 256 + tid;
    int r = cc >> 5, ch = cc & 31;
    int row = row0 + r;
    uint4 v = make_uint4(0u, 0u, 0u, 0u);
    if (row < N) v = *(const uint4*)&A[(size_t)row * HID + ch * 8];
    *(uint4*)&a_lds[r * BKP + ch * 8] = v;
  }
  __syncthreads();

  f4v acc[4][2];
#pragma unroll
  for (int rt = 0; rt < 4; ++rt)
#pragma unroll
    for (int ct = 0; ct < 2; ++ct) acc[rt][ct] = (f4v)0.f;

  for (int ks = 0; ks < 8; ++ks) {
    s8v af[4];
#pragma unroll
    for (int rt = 0; rt < 4; ++rt)
      af[rt] = *(const s8v*)&a_lds[(rt * 16 + (l & 15)) * BKP + ks * 32 + (l >> 4) * 8];
#pragma unroll
    for (int ct = 0; ct < 2; ++ct) {
      s8v bf = *(const s8v*)&Wpk[(size_t)(((w * 2 + ct) * 8 + ks) * 64 + l) * 8];
#pragma unroll
      for (int rt = 0; rt < 4; ++rt)
        acc[rt][ct] = __builtin_amdgcn_mfma_f32_16x16x32_bf16(af[rt], bf, acc[rt][ct], 0, 0, 0);
    }
  }

#pragma unroll
  for (int ct = 0; ct < 2; ++ct) {
    int col = w * 32 + ct * 16 + (l & 15);
    float bv = bias[col];
    float run = 0.f;
    int cur = -1;
#pragma unroll
    for (int rt = 0; rt < 4; ++rt)
#pragma unroll
      for (int reg = 0; reg < 4; ++reg) {
        int rrel = rt * 16 + (l >> 4) * 4 + reg;
        int g = b_s[rrel];
        if (g != cur) {
          if (cur >= 0) atomicAdd(&pool[cur * OUTD + col], run);
          run = 0.f;
          cur = g;
        }
        if (g >= 0) run += acc[rt][ct][reg] + bv;
      }
    if (cur >= 0) atomicAdd(&pool[cur * OUTD + col], run);
  }
  __syncthreads();
#pragma unroll
  for (int i = 0; i < 4; ++i) {
    int idx = tid * 4 + i;
    float v = pool[idx];
    if (v != 0.f) atomicAdd(&psum[idx], v);
  }
}

// ---------------------------------------------------------------------------
// Fused: GCN aggregation (+bias) -> LayerNorm -> ReLU -> residual (h bf16)
// Wave-per-node, HALF-WAVE edge parallelism: lanes 0-31 process edge j,
// lanes 32-63 edge j+1. Lane owns 8 fp8 channels (uint2 gather, 8B/lane).
// m8 rows pre-scaled by dinv[src] -> per edge-pair: 1 gather + 4 cvt + 4 pk_add.
// ---------------------------------------------------------------------------
__global__ __launch_bounds__(256) void k_agg_ln(
    const unsigned char* __restrict__ m8, unsigned short* __restrict__ h,
    const int* __restrict__ row_ptr, const int* __restrict__ col_idx,
    const float* __restrict__ dinv, const float* __restrict__ bias,
    const float* __restrict__ gamma, const float* __restrict__ beta, int N) {
  int w = threadIdx.x >> 6, l = threadIdx.x & 63;
  int d = blockIdx.x * 4 + w;
  if (d >= N) return;
  int half = l >> 5;        // 0 or 1
  int li = l & 31;
  int c0 = li * 8;          // 8 fp8 channels per lane
  float dv = dinv[d];

  f2v a01 = (f2v)0.f, a23 = (f2v)0.f, a45 = (f2v)0.f, a67 = (f2v)0.f;

  // self loop (m8 already carries dinv[d]) — only half 0 accumulates it
  if (!half) {
    uint2 sv = *(const uint2*)&m8[((size_t)d << 8) + c0];
    a01 = __builtin_amdgcn_cvt_pk_f32_fp8(sv.x, 0);
    a23 = __builtin_amdgcn_cvt_pk_f32_fp8(sv.x, 1);
    a45 = __builtin_amdgcn_cvt_pk_f32_fp8(sv.y, 0);
    a67 = __builtin_amdgcn_cvt_pk_f32_fp8(sv.y, 1);
  }

  int beg = row_ptr[d], end = row_ptr[d + 1];
  int jj = beg;
  // batched: 8 edges per iteration (4 edge-pairs)
  for (; jj + 8 <= end; jj += 8) {
    uint2 vv[4];
#pragma unroll
    for (int q = 0; q < 4; ++q) {
      int s0 = col_idx[jj + 2 * q];
      int s1 = col_idx[jj + 2 * q + 1];
      int s = half ? s1 : s0;
      vv[q] = *(const uint2*)&m8[((size_t)s << 8) + c0];
    }
#pragma unroll
    for (int q = 0; q < 4; ++q) {
      a01 += __builtin_amdgcn_cvt_pk_f32_fp8(vv[q].x, 0);
      a23 += __builtin_amdgcn_cvt_pk_f32_fp8(vv[q].x, 1);
      a45 += __builtin_amdgcn_cvt_pk_f32_fp8(vv[q].y, 0);
      a67 += __builtin_amdgcn_cvt_pk_f32_fp8(vv[q].y, 1);
    }
  }
  // tail: 2 edges per iteration; inactive slot gathers zeros via mask
  for (; jj < end; jj += 2) {
    int s0 = col_idx[jj];
    int s1 = (jj + 1 < end) ? col_idx[jj + 1] : -1;
    int s = half ? s1 : s0;
    uint2 v = make_uint2(0u, 0u);
    if (s >= 0) v = *(const uint2*)&m8[((size_t)s << 8) + c0];
    a01 += __builtin_amdgcn_cvt_pk_f32_fp8(v.x, 0);
    a23 += __builtin_amdgcn_cvt_pk_f32_fp8(v.x, 1);
    a45 += __builtin_amdgcn_cvt_pk_f32_fp8(v.y, 0);
    a67 += __builtin_amdgcn_cvt_pk_f32_fp8(v.y, 1);
  }

  // combine half-wave partials (lane l <-> l^32); afterwards both halves
  // hold identical per-channel sums -> 64-lane reductions count each channel
  // twice (divide by 512).
  a01[0] += __shfl_xor(a01[0], 32, 64); a01[1] += __shfl_xor(a01[1], 32, 64);
  a23[0] += __shfl_xor(a23[0], 32, 64); a23[1] += __shfl_xor(a23[1], 32, 64);
  a45[0] += __shfl_xor(a45[0], 32, 64); a45[1] += __shfl_xor(a45[1], 32, 64);
  a67[0] += __shfl_xor(a67[0], 32, 64); a67[1] += __shfl_xor(a67[1], 32, 64);

  float4 bv0 = *(const float4*)&bias[c0];
  float4 bv1 = *(const float4*)&bias[c0 + 4];
  float a[8];
  a[0] = a01[0] * dv + bv0.x; a[1] = a01[1] * dv + bv0.y;
  a[2] = a23[0] * dv + bv0.z; a[3] = a23[1] * dv + bv0.w;
  a[4] = a45[0] * dv + bv1.x; a[5] = a45[1] * dv + bv1.y;
  a[6] = a67[0] * dv + bv1.z; a[7] = a67[1] * dv + bv1.w;

  float t = 0.f;
#pragma unroll
  for (int q = 0; q < 8; ++q) t += a[q];
#pragma unroll
  for (int o = 32; o > 0; o >>= 1) t += __shfl_xor(t, o, 64);
  float mu = t * (1.f / 512.f);   // channels counted twice across halves

  float v2 = 0.f;
  float dx[8];
#pragma unroll
  for (int q = 0; q < 8; ++q) { dx[q] = a[q] - mu; v2 += dx[q] * dx[q]; }
#pragma unroll
  for (int o = 32; o > 0; o >>= 1) v2 += __shfl_xor(v2, o, 64);
  float rs = rsqrtf(v2 * (1.f / 512.f) + LN_EPS);

  if (!half) {
    float4 gv0 = *(const float4*)&gamma[c0];
    float4 gv1 = *(const float4*)&gamma[c0 + 4];
    float4 bt0 = *(const float4*)&beta[c0];
    float4 bt1 = *(const float4*)&beta[c0 + 4];
    float g[8] = {gv0.x, gv0.y, gv0.z, gv0.w, gv1.x, gv1.y, gv1.z, gv1.w};
    float bb[8] = {bt0.x, bt0.y, bt0.z, bt0.w, bt1.x, bt1.y, bt1.z, bt1.w};
    uint4 hv = *(const uint4*)&h[(size_t)d * HID + c0];
    float hr[8] = {b2f_lo(hv.x), b2f_hi(hv.x), b2f_lo(hv.y), b2f_hi(hv.y),
                   b2f_lo(hv.z), b2f_hi(hv.z), b2f_lo(hv.w), b2f_hi(hv.w)};
    unsigned short ob[8];
#pragma unroll
    for (int q = 0; q < 8; ++q)
      ob[q] = f2b(fmaxf(dx[q] * rs * g[q] + bb[q], 0.f) + hr[q]);
    *(uint4*)&h[(size_t)d * HID + c0] = *(const uint4*)ob;
  }
}

// Final: out[b][c] = psum[b][c] / count(batch==b); counts via binary search.
__global__ void k_final(const float* __restrict__ psum, const int* __restrict__ batch,
                        float* __restrict__ out, int N) {
  int t = threadIdx.x;  // 1024 = 8*128
  int b = t >> 7;
  int lo = 0, hi = N;
  while (lo < hi) { int mid = (lo + hi) >> 1; if (batch[mid] < b) lo = mid + 1; else hi = mid; }
  int lb = lo;
  lo = 0; hi = N;
  while (lo < hi) { int mid = (lo + hi) >> 1; if (batch[mid] <= b) lo = mid + 1; else hi = mid; }
  int cnt = lo - lb;
  out[t] = psum[t] / fmaxf((float)cnt, 1.f);
}

// ---------------------------------------------------------------------------
extern "C" void kernel_launch(void* const* d_in, const int* in_sizes, int n_in,
                              void* d_out, int out_size, void* d_ws, size_t ws_size,
                              hipStream_t stream) {
  const float* x      = (const float*)d_in[0];
  const int*   ei     = (const int*)d_in[1];
  const int*   nt     = (const int*)d_in[2];
  const int*   batch  = (const int*)d_in[3];
  const float* emb    = (const float*)d_in[4];
  const float* W_in   = (const float*)d_in[5];
  const float* b_in   = (const float*)d_in[6];
  const float* Ws     = (const float*)d_in[7];
  const float* bs     = (const float*)d_in[8];
  const float* gammas = (const float*)d_in[9];
  const float* betas  = (const float*)d_in[10];
  const float* W_out  = (const float*)d_in[11];
  const float* b_out  = (const float*)d_in[12];
  float* out = (float*)d_out;

  const int N = in_sizes[2];
  const int E = in_sizes[1] / 2;
  const int nbuck = (N + 255) >> 8;
  const int epb = (E + NBLK - 1) / NBLK;

  auto align = [](size_t v) { return (v + 255) & ~(size_t)255; };
  char* p = (char*)d_ws;
  unsigned short* h = (unsigned short*)p; p += align((size_t)N * HID * 2);
  unsigned char* m8 = (unsigned char*)p;  p += align((size_t)N * HID);
  unsigned short* pk_in  = (unsigned short*)p; p += align((size_t)T_IN * 2);
  unsigned short* pk_sq  = (unsigned short*)p; p += align((size_t)3 * T_SQ * 2);
  unsigned short* pk_out = (unsigned short*)p; p += align((size_t)T_OUT * 2);
  float* dinv = (float*)p;        p += align((size_t)N * 4);
  int* row_ptr = (int*)p;         p += align((size_t)(N + 1) * 4);
  int* col_idx = (int*)p;         p += align((size_t)E * 4);
  unsigned int* pairs = (unsigned int*)p; p += align((size_t)E * 4);
  int* blk_cnt = (int*)p;         p += align((size_t)NBLK * 256 * 4);
  int* blk_off = (int*)p;         p += align((size_t)NBLK * 256 * 4);
  int* bucket_cnt = (int*)p;      p += align(256 * 4);
  int* bucket_base = (int*)p;     p += align(257 * 4);
  float* psum = (float*)p;        p += align((size_t)NGRAPH * OUTD * 4);

  hipMemsetAsync(psum, 0, (size_t)NGRAPH * OUTD * 4, stream);

  // weight packing: single launch for all weights
  {
    int total = T_IN + 3 * T_SQ + T_OUT;
    k_pack_all<<<(total + 255) / 256, 256, 0, stream>>>(W_in, Ws, W_out,
                                                        pk_in, pk_sq, pk_out);
  }

  // CSR build (two-level counting sort, no global data atomics)
  k_b1<<<NBLK, 256, 0, stream>>>(ei + E, blk_cnt, E, epb);
  k_bsum<<<nbuck, 256, 0, stream>>>(blk_cnt, bucket_cnt);
  k_bscan<<<1, 256, 0, stream>>>(bucket_cnt, bucket_base, row_ptr, N, nbuck, E);
  k_boff<<<nbuck, 256, 0, stream>>>(blk_cnt, bucket_base, blk_off);
  k_b3<<<NBLK, 256, 0, stream>>>(ei, blk_off, pairs, E, epb);
  k_b4<<<nbuck, 256, 0, stream>>>(pairs, bucket_base, row_ptr, dinv, col_idx, N);

  const int GB = (N + 63) / 64;
  k_mfma_in<<<GB, 256, 0, stream>>>(x, nt, emb, pk_in, b_in, h, N);

  for (int lyr = 0; lyr < NLAYER; ++lyr) {
    k_mfma_sq<<<GB, 256, 0, stream>>>(h, pk_sq + (size_t)lyr * T_SQ, dinv, m8, N);
    k_agg_ln<<<(N + 3) / 4, 256, 0, stream>>>(m8, h, row_ptr, col_idx, dinv,
                                              bs + (size_t)lyr * HID, gammas + (size_t)lyr * HID,
                                              betas + (size_t)lyr * HID, N);
  }

  k_mfma_out_pool<<<GB, 256, 0, stream>>>(h, pk_out, b_out, batch, psum, N);
  k_final<<<1, 1024, 0, stream>>>(psum, batch, out, N);
}

// Round 10
// 369.722 us; speedup vs baseline: 1.0129x; 1.0129x over previous
//
#include <hip/hip_runtime.h>
#include <math.h>

// Problem constants (match reference)
#define HID 256
#define DXIN 128
#define EMBD 32
#define OUTD 128
#define NLAYER 3
#define NGRAPH 8
#define LN_EPS 1e-5f
#define BKP 264   // LDS row stride (bf16 elems): 33 quads, 33%8==1 -> uniform banks
#define NBLK 256  // blocks for edge-binning passes
#define TILEB 13  // src locality tile = src >> 13 (8192 nodes = 2MB fp8, fits XCD L2)
#define NTILE 8

typedef short s8v __attribute__((ext_vector_type(8)));
typedef float f4v __attribute__((ext_vector_type(4)));
typedef float f2v __attribute__((ext_vector_type(2)));

__device__ __forceinline__ float b2f_lo(unsigned int u) {
  return __builtin_bit_cast(float, u << 16);
}
__device__ __forceinline__ float b2f_hi(unsigned int u) {
  return __builtin_bit_cast(float, u & 0xffff0000u);
}
__device__ __forceinline__ unsigned short f2b(float f) {
  unsigned int x = __builtin_bit_cast(unsigned int, f);
  unsigned int lsb = (x >> 16) & 1u;
  x += 0x7fffu + lsb;
  return (unsigned short)(x >> 16);
}

// ---------------------------------------------------------------------------
// CSR build via two-level counting sort (no global data atomics).
// bucket = dst >> 8 (<=256 buckets), dloc = dst & 255.
// ---------------------------------------------------------------------------
__global__ __launch_bounds__(256) void k_b1(const int* __restrict__ dst,
                                            int* __restrict__ blk_cnt, int E, int epb) {
  __shared__ int hist[256];
  int blk = blockIdx.x, tid = threadIdx.x;
  hist[tid] = 0;
  __syncthreads();
  int beg = blk * epb, end = min(E, beg + epb);
  for (int i = beg + tid; i < end; i += 256)
    atomicAdd(&hist[dst[i] >> 8], 1);
  __syncthreads();
  blk_cnt[blk * 256 + tid] = hist[tid];
}

__global__ __launch_bounds__(256) void k_bsum(const int* __restrict__ blk_cnt,
                                              int* __restrict__ bucket_cnt) {
  __shared__ int red[4];
  int b = blockIdx.x, tid = threadIdx.x;
  int v = blk_cnt[tid * 256 + b];
#pragma unroll
  for (int o = 32; o > 0; o >>= 1) v += __shfl_xor(v, o, 64);
  if ((tid & 63) == 0) red[tid >> 6] = v;
  __syncthreads();
  if (tid == 0) bucket_cnt[b] = red[0] + red[1] + red[2] + red[3];
}

__global__ __launch_bounds__(256) void k_bscan(const int* __restrict__ bucket_cnt,
                                               int* __restrict__ bucket_base,
                                               int* __restrict__ row_ptr,
                                               int N, int nbuck, int E) {
  __shared__ int s[256];
  int tid = threadIdx.x;
  int v = (tid < nbuck) ? bucket_cnt[tid] : 0;
  s[tid] = v;
  __syncthreads();
  for (int off = 1; off < 256; off <<= 1) {
    int t = (tid >= off) ? s[tid - off] : 0;
    __syncthreads();
    s[tid] += t;
    __syncthreads();
  }
  if (tid < nbuck) bucket_base[tid] = s[tid] - v;
  if (tid == 0) { bucket_base[nbuck] = E; row_ptr[N] = E; }
}

__global__ __launch_bounds__(256) void k_boff(const int* __restrict__ blk_cnt,
                                              const int* __restrict__ bucket_base,
                                              int* __restrict__ blk_off) {
  __shared__ int s[256];
  int b = blockIdx.x, tid = threadIdx.x;
  int v = blk_cnt[tid * 256 + b];
  s[tid] = v;
  __syncthreads();
  for (int off = 1; off < 256; off <<= 1) {
    int t = (tid >= off) ? s[tid - off] : 0;
    __syncthreads();
    s[tid] += t;
    __syncthreads();
  }
  blk_off[tid * 256 + b] = bucket_base[b] + s[tid] - v;
}

__global__ __launch_bounds__(256) void k_b3(const int* __restrict__ ei,
                                            const int* __restrict__ blk_off,
                                            unsigned int* __restrict__ pairs,
                                            int E, int epb) {
  __shared__ int cur[256];
  int blk = blockIdx.x, tid = threadIdx.x;
  cur[tid] = blk_off[blk * 256 + tid];
  __syncthreads();
  int beg = blk * epb, end = min(E, beg + epb);
  for (int i = beg + tid; i < end; i += 256) {
    int s = ei[i];
    int d = ei[E + i];
    int pos = atomicAdd(&cur[d >> 8], 1);
    pairs[pos] = (unsigned int)s | ((unsigned int)(d & 255) << 16);
  }
}

// Pass 4: per-bucket local CSR (LDS atomics only) + row_ptr + dinv + col_idx.
// Edges within each row are grouped by src-tile (src>>TILEB) so that the
// aggregation kernel's gathers have cross-wave temporal locality in L2.
__global__ __launch_bounds__(256) void k_b4(const unsigned int* __restrict__ pairs,
                                            const int* __restrict__ bucket_base,
                                            int* __restrict__ row_ptr,
                                            float* __restrict__ dinv,
                                            int* __restrict__ col_idx, int N) {
  __shared__ int cnt[256][NTILE];   // per (dloc, src-tile) counts -> cursors
  __shared__ int s[256];
  int b = blockIdx.x, tid = threadIdx.x;
  int base = bucket_base[b], end = bucket_base[b + 1];
#pragma unroll
  for (int t = 0; t < NTILE; ++t) cnt[tid][t] = 0;
  __syncthreads();
  for (int i = base + tid; i < end; i += 256) {
    unsigned int w = pairs[i];
    atomicAdd(&cnt[w >> 16][(w & 0xFFFFu) >> TILEB], 1);
  }
  __syncthreads();
  int c = 0;
#pragma unroll
  for (int t = 0; t < NTILE; ++t) c += cnt[tid][t];
  s[tid] = c;
  __syncthreads();
  for (int off = 1; off < 256; off <<= 1) {
    int t = (tid >= off) ? s[tid - off] : 0;
    __syncthreads();
    s[tid] += t;
    __syncthreads();
  }
  int excl = s[tid] - c;
  int d = (b << 8) + tid;
  if (d < N) {
    row_ptr[d] = base + excl;
    dinv[d] = rsqrtf((float)(c + 1));
  }
  // per-row tile cursors (serial 8-slot prefix, thread owns its dloc)
  int run = base + excl;
#pragma unroll
  for (int t = 0; t < NTILE; ++t) { int cc = cnt[tid][t]; cnt[tid][t] = run; run += cc; }
  __syncthreads();
  for (int i = base + tid; i < end; i += 256) {
    unsigned int w = pairs[i];
    int src = (int)(w & 0xFFFFu);
    int pos = atomicAdd(&cnt[w >> 16][src >> TILEB], 1);
    col_idx[pos] = src;
  }
}

// ---------------------------------------------------------------------------
// Weight pack (ALL weights in one launch): W [K][C] fp32 -> bf16 B-fragments.
// ---------------------------------------------------------------------------
#define T_IN  (16 * 5 * 512)
#define T_SQ  (16 * 8 * 512)
#define T_OUT (8 * 8 * 512)
__global__ void k_pack_all(const float* __restrict__ W_in, const float* __restrict__ Ws,
                           const float* __restrict__ W_out,
                           unsigned short* __restrict__ pk_in,
                           unsigned short* __restrict__ pk_sq,
                           unsigned short* __restrict__ pk_out) {
  int t = blockIdx.x * 256 + threadIdx.x;
  const float* W;
  unsigned short* dst;
  int C, NKS;
  if (t < T_IN) {
    W = W_in; dst = pk_in; C = HID; NKS = 5;
  } else if (t < T_IN + 3 * T_SQ) {
    int tt = t - T_IN;
    int lyr = tt / T_SQ;
    t = tt - lyr * T_SQ;
    W = Ws + (size_t)lyr * HID * HID; dst = pk_sq + (size_t)lyr * T_SQ; C = HID; NKS = 8;
  } else if (t < T_IN + 3 * T_SQ + T_OUT) {
    t = t - T_IN - 3 * T_SQ;
    W = W_out; dst = pk_out; C = OUTD; NKS = 8;
  } else {
    return;
  }
  int j = t & 7;
  int l = (t >> 3) & 63;
  int rest = t >> 9;
  int ks = rest % NKS;
  int ct = rest / NKS;
  int k = ks * 32 + ((l >> 4) << 3) + j;
  int c = ct * 16 + (l & 15);
  dst[t] = f2b(W[(size_t)k * C + c]);
}

// ---------------------------------------------------------------------------
// MFMA GEMM: input projection  h = relu(concat(x, emb[nt]) @ W_in + b_in)
// ---------------------------------------------------------------------------
__global__ __launch_bounds__(256) void k_mfma_in(
    const float* __restrict__ x, const int* __restrict__ nt, const float* __restrict__ emb,
    const unsigned short* __restrict__ Wpk, const float* __restrict__ bias,
    unsigned short* __restrict__ h, int N) {
  __shared__ unsigned short a_lds[64 * BKP];
  int tid = threadIdx.x;
  int w = tid >> 6, l = tid & 63;
  int row0 = blockIdx.x * 64;

  for (int i = 0; i < 4; ++i) {
    int cc = i * 256 + tid;
    int r = cc >> 4, ch = cc & 15;
    int row = row0 + r;
    unsigned short tmp[8];
    if (row < N) {
      const float* xr = &x[(size_t)row * DXIN + ch * 8];
      float4 v0 = *(const float4*)xr;
      float4 v1 = *(const float4*)(xr + 4);
      tmp[0] = f2b(v0.x); tmp[1] = f2b(v0.y); tmp[2] = f2b(v0.z); tmp[3] = f2b(v0.w);
      tmp[4] = f2b(v1.x); tmp[5] = f2b(v1.y); tmp[6] = f2b(v1.z); tmp[7] = f2b(v1.w);
    } else {
      for (int q = 0; q < 8; ++q) tmp[q] = 0;
    }
    *(uint4*)&a_lds[r * BKP + ch * 8] = *(const uint4*)tmp;
  }
  {
    int r = tid >> 2, ch = tid & 3;
    int row = row0 + r;
    unsigned short tmp[8];
    if (row < N) {
      int typ = nt[row];
      const float* er = &emb[typ * EMBD + ch * 8];
      float4 v0 = *(const float4*)er;
      float4 v1 = *(const float4*)(er + 4);
      tmp[0] = f2b(v0.x); tmp[1] = f2b(v0.y); tmp[2] = f2b(v0.z); tmp[3] = f2b(v0.w);
      tmp[4] = f2b(v1.x); tmp[5] = f2b(v1.y); tmp[6] = f2b(v1.z); tmp[7] = f2b(v1.w);
    } else {
      for (int q = 0; q < 8; ++q) tmp[q] = 0;
    }
    *(uint4*)&a_lds[r * BKP + DXIN + ch * 8] = *(const uint4*)tmp;
  }
  __syncthreads();

  f4v acc[4][4];
#pragma unroll
  for (int rt = 0; rt < 4; ++rt)
#pragma unroll
    for (int ct = 0; ct < 4; ++ct) acc[rt][ct] = (f4v)0.f;

  for (int ks = 0; ks < 5; ++ks) {
    s8v af[4];
#pragma unroll
    for (int rt = 0; rt < 4; ++rt)
      af[rt] = *(const s8v*)&a_lds[(rt * 16 + (l & 15)) * BKP + ks * 32 + (l >> 4) * 8];
#pragma unroll
    for (int ct = 0; ct < 4; ++ct) {
      s8v bf = *(const s8v*)&Wpk[(size_t)(((w * 4 + ct) * 5 + ks) * 64 + l) * 8];
#pragma unroll
      for (int rt = 0; rt < 4; ++rt)
        acc[rt][ct] = __builtin_amdgcn_mfma_f32_16x16x32_bf16(af[rt], bf, acc[rt][ct], 0, 0, 0);
    }
  }
  __syncthreads();

#pragma unroll
  for (int rt = 0; rt < 4; ++rt)
#pragma unroll
    for (int ct = 0; ct < 4; ++ct) {
      int col = w * 64 + ct * 16 + (l & 15);
      float bv = bias[col];
#pragma unroll
      for (int reg = 0; reg < 4; ++reg) {
        int r = rt * 16 + (l >> 4) * 4 + reg;
        a_lds[r * BKP + col] = f2b(fmaxf(acc[rt][ct][reg] + bv, 0.f));
      }
    }
  __syncthreads();
  for (int i = 0; i < 8; ++i) {
    int cc = i * 256 + tid;
    int r = cc >> 5, ch = cc & 31;
    int row = row0 + r;
    if (row < N)
      *(uint4*)&h[(size_t)row * HID + ch * 8] = *(const uint4*)&a_lds[r * BKP + ch * 8];
  }
}

// ---------------------------------------------------------------------------
// MFMA GEMM: square layer  m8 = fp8((h @ W) * dinv[row])  (pre-scaled by src norm)
// ---------------------------------------------------------------------------
__global__ __launch_bounds__(256) void k_mfma_sq(
    const unsigned short* __restrict__ A, const unsigned short* __restrict__ Wpk,
    const float* __restrict__ dinv, unsigned char* __restrict__ m8, int N) {
  __shared__ unsigned short a_lds[64 * BKP];
  int tid = threadIdx.x;
  int w = tid >> 6, l = tid & 63;
  int row0 = blockIdx.x * 64;

  for (int i = 0; i < 8; ++i) {
    int cc = i * 256 + tid;
    int r = cc >> 5, ch = cc & 31;
    int row = row0 + r;
    uint4 v = make_uint4(0u, 0u, 0u, 0u);
    if (row < N) v = *(const uint4*)&A[(size_t)row * HID + ch * 8];
    *(uint4*)&a_lds[r * BKP + ch * 8] = v;
  }
  __syncthreads();

  f4v acc[4][4];
#pragma unroll
  for (int rt = 0; rt < 4; ++rt)
#pragma unroll
    for (int ct = 0; ct < 4; ++ct) acc[rt][ct] = (f4v)0.f;

  for (int ks = 0; ks < 8; ++ks) {
    s8v af[4];
#pragma unroll
    for (int rt = 0; rt < 4; ++rt)
      af[rt] = *(const s8v*)&a_lds[(rt * 16 + (l & 15)) * BKP + ks * 32 + (l >> 4) * 8];
#pragma unroll
    for (int ct = 0; ct < 4; ++ct) {
      s8v bf = *(const s8v*)&Wpk[(size_t)(((w * 4 + ct) * 8 + ks) * 64 + l) * 8];
#pragma unroll
      for (int rt = 0; rt < 4; ++rt)
        acc[rt][ct] = __builtin_amdgcn_mfma_f32_16x16x32_bf16(af[rt], bf, acc[rt][ct], 0, 0, 0);
    }
  }
  __syncthreads();

  // transpose via LDS (bf16), then scale by dinv[row] + convert to fp8 on store
#pragma unroll
  for (int rt = 0; rt < 4; ++rt)
#pragma unroll
    for (int ct = 0; ct < 4; ++ct) {
      int col = w * 64 + ct * 16 + (l & 15);
#pragma unroll
      for (int reg = 0; reg < 4; ++reg) {
        int r = rt * 16 + (l >> 4) * 4 + reg;
        a_lds[r * BKP + col] = f2b(acc[rt][ct][reg]);
      }
    }
  __syncthreads();
  for (int i = 0; i < 8; ++i) {
    int cc = i * 256 + tid;
    int r = cc >> 5, ch = cc & 31;
    int row = row0 + r;
    if (row < N) {
      float dv = dinv[row];
      uint4 v = *(const uint4*)&a_lds[r * BKP + ch * 8];
      float f0 = b2f_lo(v.x) * dv, f1 = b2f_hi(v.x) * dv;
      float f2 = b2f_lo(v.y) * dv, f3 = b2f_hi(v.y) * dv;
      float f4 = b2f_lo(v.z) * dv, f5 = b2f_hi(v.z) * dv;
      float f6 = b2f_lo(v.w) * dv, f7 = b2f_hi(v.w) * dv;
      unsigned int p0 = 0, p1 = 0;
      p0 = __builtin_amdgcn_cvt_pk_fp8_f32(f0, f1, p0, 0);
      p0 = __builtin_amdgcn_cvt_pk_fp8_f32(f2, f3, p0, 1);
      p1 = __builtin_amdgcn_cvt_pk_fp8_f32(f4, f5, p1, 0);
      p1 = __builtin_amdgcn_cvt_pk_fp8_f32(f6, f7, p1, 1);
      *(uint2*)&m8[(size_t)row * HID + ch * 8] = make_uint2(p0, p1);
    }
  }
}

// ---------------------------------------------------------------------------
// MFMA GEMM: output layer (C=128) + bias + mean-pool partials via LDS bins.
// ---------------------------------------------------------------------------
__global__ __launch_bounds__(256) void k_mfma_out_pool(
    const unsigned short* __restrict__ A, const unsigned short* __restrict__ Wpk,
    const float* __restrict__ bias, const int* __restrict__ batch,
    float* __restrict__ psum, int N) {
  __shared__ unsigned short a_lds[64 * BKP];
  __shared__ float pool[NGRAPH * OUTD];
  __shared__ int b_s[64];
  int tid = threadIdx.x;
  int w = tid >> 6, l = tid & 63;
  int row0 = blockIdx.x * 64;

#pragma unroll
  for (int i = 0; i < 4; ++i) pool[tid * 4 + i] = 0.f;
  if (tid < 64) b_s[tid] = (row0 + tid < N) ? batch[row0 + tid] : -1;

  for (int i = 0; i < 8; ++i) {
    int cc = i * 256 + tid;
    int r = cc >> 5, ch = cc & 31;
    int row = row0 + r;
    uint4 v = make_uint4(0u, 0u, 0u, 0u);
    if (row < N) v = *(const uint4*)&A[(size_t)row * HID + ch * 8];
    *(uint4*)&a_lds[r * BKP + ch * 8] = v;
  }
  __syncthreads();

  f4v acc[4][2];
#pragma unroll
  for (int rt = 0; rt < 4; ++rt)
#pragma unroll
    for (int ct = 0; ct < 2; ++ct) acc[rt][ct] = (f4v)0.f;

  for (int ks = 0; ks < 8; ++ks) {
    s8v af[4];
#pragma unroll
    for (int rt = 0; rt < 4; ++rt)
      af[rt] = *(const s8v*)&a_lds[(rt * 16 + (l & 15)) * BKP + ks * 32 + (l >> 4) * 8];
#pragma unroll
    for (int ct = 0; ct < 2; ++ct) {
      s8v bf = *(const s8v*)&Wpk[(size_t)(((w * 2 + ct) * 8 + ks) * 64 + l) * 8];
#pragma unroll
      for (int rt = 0; rt < 4; ++rt)
        acc[rt][ct] = __builtin_amdgcn_mfma_f32_16x16x32_bf16(af[rt], bf, acc[rt][ct], 0, 0, 0);
    }
  }

#pragma unroll
  for (int ct = 0; ct < 2; ++ct) {
    int col = w * 32 + ct * 16 + (l & 15);
    float bv = bias[col];
    float run = 0.f;
    int cur = -1;
#pragma unroll
    for (int rt = 0; rt < 4; ++rt)
#pragma unroll
      for (int reg = 0; reg < 4; ++reg) {
        int rrel = rt * 16 + (l >> 4) * 4 + reg;
        int g = b_s[rrel];
        if (g != cur) {
          if (cur >= 0) atomicAdd(&pool[cur * OUTD + col], run);
          run = 0.f;
          cur = g;
        }
        if (g >= 0) run += acc[rt][ct][reg] + bv;
      }
    if (cur >= 0) atomicAdd(&pool[cur * OUTD + col], run);
  }
  __syncthreads();
#pragma unroll
  for (int i = 0; i < 4; ++i) {
    int idx = tid * 4 + i;
    float v = pool[idx];
    if (v != 0.f) atomicAdd(&psum[idx], v);
  }
}

// ---------------------------------------------------------------------------
// Fused: GCN aggregation (+bias) -> LayerNorm -> ReLU -> residual (h bf16)
// Wave-per-node; lane owns 4 channels; m8 rows pre-scaled by dinv[src] ->
// per-edge work is one dword gather + 2 cvt + 4 add. 8-deep load batching.
// (round-8 form — the half-wave variant regressed)
// ---------------------------------------------------------------------------
__global__ __launch_bounds__(256) void k_agg_ln(
    const unsigned char* __restrict__ m8, unsigned short* __restrict__ h,
    const int* __restrict__ row_ptr, const int* __restrict__ col_idx,
    const float* __restrict__ dinv, const float* __restrict__ bias,
    const float* __restrict__ gamma, const float* __restrict__ beta, int N) {
  int w = threadIdx.x >> 6, l = threadIdx.x & 63;
  int d = blockIdx.x * 4 + w;
  if (d >= N) return;
  int c0 = l * 4;
  float dv = dinv[d];

  // self loop (m8 already carries dinv[d])
  unsigned int sv = *(const unsigned int*)&m8[((size_t)d << 8) + c0];
  f2v slo = __builtin_amdgcn_cvt_pk_f32_fp8(sv, 0);
  f2v shi = __builtin_amdgcn_cvt_pk_f32_fp8(sv, 1);
  float a0 = slo[0];
  float a1 = slo[1];
  float a2 = shi[0];
  float a3 = shi[1];

  int beg = row_ptr[d], end = row_ptr[d + 1];
  int jj = beg;
  for (; jj + 8 <= end; jj += 8) {
    unsigned int vv[8];
#pragma unroll
    for (int q = 0; q < 8; ++q) {
      int s = col_idx[jj + q];
      vv[q] = *(const unsigned int*)&m8[((size_t)s << 8) + c0];
    }
#pragma unroll
    for (int q = 0; q < 8; ++q) {
      f2v lo = __builtin_amdgcn_cvt_pk_f32_fp8(vv[q], 0);
      f2v hi = __builtin_amdgcn_cvt_pk_f32_fp8(vv[q], 1);
      a0 += lo[0];
      a1 += lo[1];
      a2 += hi[0];
      a3 += hi[1];
    }
  }
  for (; jj < end; ++jj) {
    int s = col_idx[jj];
    unsigned int v = *(const unsigned int*)&m8[((size_t)s << 8) + c0];
    f2v lo = __builtin_amdgcn_cvt_pk_f32_fp8(v, 0);
    f2v hi = __builtin_amdgcn_cvt_pk_f32_fp8(v, 1);
    a0 += lo[0];
    a1 += lo[1];
    a2 += hi[0];
    a3 += hi[1];
  }

  float4 bv = *(const float4*)&bias[c0];
  a0 = a0 * dv + bv.x;
  a1 = a1 * dv + bv.y;
  a2 = a2 * dv + bv.z;
  a3 = a3 * dv + bv.w;

  float t = a0 + a1 + a2 + a3;
#pragma unroll
  for (int o = 32; o > 0; o >>= 1) t += __shfl_xor(t, o, 64);
  float mu = t * (1.f / 256.f);
  float d0 = a0 - mu, d1 = a1 - mu, d2 = a2 - mu, d3 = a3 - mu;
  float v2 = d0 * d0 + d1 * d1 + d2 * d2 + d3 * d3;
#pragma unroll
  for (int o = 32; o > 0; o >>= 1) v2 += __shfl_xor(v2, o, 64);
  float rs = rsqrtf(v2 * (1.f / 256.f) + LN_EPS);

  float4 gv = *(const float4*)&gamma[c0];
  float4 bt = *(const float4*)&beta[c0];
  uint2 hv = *(const uint2*)&h[(size_t)d * HID + c0];
  float y0 = fmaxf(d0 * rs * gv.x + bt.x, 0.f) + b2f_lo(hv.x);
  float y1 = fmaxf(d1 * rs * gv.y + bt.y, 0.f) + b2f_hi(hv.x);
  float y2 = fmaxf(d2 * rs * gv.z + bt.z, 0.f) + b2f_lo(hv.y);
  float y3 = fmaxf(d3 * rs * gv.w + bt.w, 0.f) + b2f_hi(hv.y);
  uint2 ov;
  ov.x = (unsigned int)f2b(y0) | ((unsigned int)f2b(y1) << 16);
  ov.y = (unsigned int)f2b(y2) | ((unsigned int)f2b(y3) << 16);
  *(uint2*)&h[(size_t)d * HID + c0] = ov;
}

// Final: out[b][c] = psum[b][c] / count(batch==b); counts via binary search.
__global__ void k_final(const float* __restrict__ psum, const int* __restrict__ batch,
                        float* __restrict__ out, int N) {
  int t = threadIdx.x;  // 1024 = 8*128
  int b = t >> 7;
  int lo = 0, hi = N;
  while (lo < hi) { int mid = (lo + hi) >> 1; if (batch[mid] < b) lo = mid + 1; else hi = mid; }
  int lb = lo;
  lo = 0; hi = N;
  while (lo < hi) { int mid = (lo + hi) >> 1; if (batch[mid] <= b) lo = mid + 1; else hi = mid; }
  int cnt = lo - lb;
  out[t] = psum[t] / fmaxf((float)cnt, 1.f);
}

// ---------------------------------------------------------------------------
extern "C" void kernel_launch(void* const* d_in, const int* in_sizes, int n_in,
                              void* d_out, int out_size, void* d_ws, size_t ws_size,
                              hipStream_t stream) {
  const float* x      = (const float*)d_in[0];
  const int*   ei     = (const int*)d_in[1];
  const int*   nt     = (const int*)d_in[2];
  const int*   batch  = (const int*)d_in[3];
  const float* emb    = (const float*)d_in[4];
  const float* W_in   = (const float*)d_in[5];
  const float* b_in   = (const float*)d_in[6];
  const float* Ws     = (const float*)d_in[7];
  const float* bs     = (const float*)d_in[8];
  const float* gammas = (const float*)d_in[9];
  const float* betas  = (const float*)d_in[10];
  const float* W_out  = (const float*)d_in[11];
  const float* b_out  = (const float*)d_in[12];
  float* out = (float*)d_out;

  const int N = in_sizes[2];
  const int E = in_sizes[1] / 2;
  const int nbuck = (N + 255) >> 8;
  const int epb = (E + NBLK - 1) / NBLK;

  auto align = [](size_t v) { return (v + 255) & ~(size_t)255; };
  char* p = (char*)d_ws;
  unsigned short* h = (unsigned short*)p; p += align((size_t)N * HID * 2);
  unsigned char* m8 = (unsigned char*)p;  p += align((size_t)N * HID);
  unsigned short* pk_in  = (unsigned short*)p; p += align((size_t)T_IN * 2);
  unsigned short* pk_sq  = (unsigned short*)p; p += align((size_t)3 * T_SQ * 2);
  unsigned short* pk_out = (unsigned short*)p; p += align((size_t)T_OUT * 2);
  float* dinv = (float*)p;        p += align((size_t)N * 4);
  int* row_ptr = (int*)p;         p += align((size_t)(N + 1) * 4);
  int* col_idx = (int*)p;         p += align((size_t)E * 4);
  unsigned int* pairs = (unsigned int*)p; p += align((size_t)E * 4);
  int* blk_cnt = (int*)p;         p += align((size_t)NBLK * 256 * 4);
  int* blk_off = (int*)p;         p += align((size_t)NBLK * 256 * 4);
  int* bucket_cnt = (int*)p;      p += align(256 * 4);
  int* bucket_base = (int*)p;     p += align(257 * 4);
  float* psum = (float*)p;        p += align((size_t)NGRAPH * OUTD * 4);

  hipMemsetAsync(psum, 0, (size_t)NGRAPH * OUTD * 4, stream);

  // weight packing: single launch for all weights
  {
    int total = T_IN + 3 * T_SQ + T_OUT;
    k_pack_all<<<(total + 255) / 256, 256, 0, stream>>>(W_in, Ws, W_out,
                                                        pk_in, pk_sq, pk_out);
  }

  // CSR build (two-level counting sort, no global data atomics)
  k_b1<<<NBLK, 256, 0, stream>>>(ei + E, blk_cnt, E, epb);
  k_bsum<<<nbuck, 256, 0, stream>>>(blk_cnt, bucket_cnt);
  k_bscan<<<1, 256, 0, stream>>>(bucket_cnt, bucket_base, row_ptr, N, nbuck, E);
  k_boff<<<nbuck, 256, 0, stream>>>(blk_cnt, bucket_base, blk_off);
  k_b3<<<NBLK, 256, 0, stream>>>(ei, blk_off, pairs, E, epb);
  k_b4<<<nbuck, 256, 0, stream>>>(pairs, bucket_base, row_ptr, dinv, col_idx, N);

  const int GB = (N + 63) / 64;
  k_mfma_in<<<GB, 256, 0, stream>>>(x, nt, emb, pk_in, b_in, h, N);

  for (int lyr = 0; lyr < NLAYER; ++lyr) {
    k_mfma_sq<<<GB, 256, 0, stream>>>(h, pk_sq + (size_t)lyr * T_SQ, dinv, m8, N);
    k_agg_ln<<<(N + 3) / 4, 256, 0, stream>>>(m8, h, row_ptr, col_idx, dinv,
                                              bs + (size_t)lyr * HID, gammas + (size_t)lyr * HID,
                                              betas + (size_t)lyr * HID, N);
  }

  k_mfma_out_pool<<<GB, 256, 0, stream>>>(h, pk_out, b_out, batch, psum, N);
  k_final<<<1, 1024, 0, stream>>>(psum, batch, out, N);
}